// Round 1
// baseline (1073.998 us; speedup 1.0000x reference)
//
#include <hip/hip_runtime.h>

#define Bd 4
#define Cd 256
#define Hd 256
#define Wd 256
#define HW 65536
#define CM 64
#define KK 9

// ---------------- Kernel A: 1x1 compression: comp[b,o,s] = sum_c x[b,c,s]*w_comp[o,c]
__global__ __launch_bounds__(256) void compress_kernel(
    const float* __restrict__ x, const float* __restrict__ w_comp,
    float* __restrict__ comp)
{
    int gid = blockIdx.x * 256 + threadIdx.x;   // 0..262143
    int b = gid >> 16;
    int s = gid & (HW - 1);
    const float* xb = x + (size_t)b * Cd * HW + s;
    float acc[CM];
#pragma unroll
    for (int o = 0; o < CM; ++o) acc[o] = 0.f;
    for (int c = 0; c < Cd; c += 4) {
        float x0 = xb[(size_t)(c + 0) * HW];
        float x1 = xb[(size_t)(c + 1) * HW];
        float x2 = xb[(size_t)(c + 2) * HW];
        float x3 = xb[(size_t)(c + 3) * HW];
#pragma unroll
        for (int o = 0; o < CM; ++o) {
            const float* wr = w_comp + o * Cd + c;   // uniform -> s_load
            acc[o] = fmaf(x0, wr[0], acc[o]);
            acc[o] = fmaf(x1, wr[1], acc[o]);
            acc[o] = fmaf(x2, wr[2], acc[o]);
            acc[o] = fmaf(x3, wr[3], acc[o]);
        }
    }
    float* ob = comp + (size_t)b * CM * HW + s;
#pragma unroll
    for (int o = 0; o < CM; ++o) ob[(size_t)o * HW] = acc[o];
}

// ---------------- Kernel B: 3x3 conv (zero pad) + bias + softmax over 9 taps
// kw stored in (B, KK, H, W) layout (same as reference pre-reshape)
__global__ __launch_bounds__(256) void kwgen_kernel(
    const float* __restrict__ comp, const float* __restrict__ w_gen,
    const float* __restrict__ b_gen, float* __restrict__ kw)
{
    int gid = blockIdx.x * 256 + threadIdx.x;
    int b = gid >> 16;
    int s = gid & (HW - 1);
    int h = s >> 8;
    int w = s & 255;
    const float* cb = comp + (size_t)b * CM * HW;
    float acc[KK];
#pragma unroll
    for (int t = 0; t < KK; ++t) acc[t] = b_gen[t];
    int hm = h - 1, hp = h + 1, wm = w - 1, wp = w + 1;
    bool hmv = hm >= 0, hpv = hp < Hd, wmv = wm >= 0, wpv = wp < Wd;
    for (int ci = 0; ci < CM; ++ci) {
        const float* cc = cb + (size_t)ci * HW;
        float nb[9];
        nb[0] = (hmv && wmv) ? cc[hm * Wd + wm] : 0.f;
        nb[1] = (hmv)        ? cc[hm * Wd + w ] : 0.f;
        nb[2] = (hmv && wpv) ? cc[hm * Wd + wp] : 0.f;
        nb[3] = (wmv)        ? cc[h  * Wd + wm] : 0.f;
        nb[4] =                cc[h  * Wd + w ];
        nb[5] = (wpv)        ? cc[h  * Wd + wp] : 0.f;
        nb[6] = (hpv && wmv) ? cc[hp * Wd + wm] : 0.f;
        nb[7] = (hpv)        ? cc[hp * Wd + w ] : 0.f;
        nb[8] = (hpv && wpv) ? cc[hp * Wd + wp] : 0.f;
        const float* wg = w_gen + ci * 9;        // + t*CM*9 + p, uniform -> s_load
#pragma unroll
        for (int t = 0; t < KK; ++t) {
            const float* wt = wg + t * CM * 9;
#pragma unroll
            for (int p = 0; p < 9; ++p)
                acc[t] = fmaf(nb[p], wt[p], acc[t]);
        }
    }
    // softmax over the 9 taps
    float m = acc[0];
#pragma unroll
    for (int t = 1; t < KK; ++t) m = fmaxf(m, acc[t]);
    float sum = 0.f;
#pragma unroll
    for (int t = 0; t < KK; ++t) { acc[t] = __expf(acc[t] - m); sum += acc[t]; }
    float inv = 1.f / sum;
    float* ob = kw + (size_t)b * KK * HW + s;
#pragma unroll
    for (int t = 0; t < KK; ++t) ob[(size_t)t * HW] = acc[t] * inv;
}

// ---------------- Kernel C: view-scramble gather + hamming renorm + reflect-pad aggregation
__global__ __launch_bounds__(256) void agg_kernel(
    const float* __restrict__ x, const float* __restrict__ kw,
    float* __restrict__ out)
{
    const float HAM[9] = {0.0064f, 0.08f, 0.0064f,
                          0.08f,   1.0f,  0.08f,
                          0.0064f, 0.08f, 0.0064f};
    int gid = blockIdx.x * 256 + threadIdx.x;
    int b = gid >> 16;
    int s = gid & (HW - 1);
    int h = s >> 8;
    int w = s & 255;
    // .view reinterpret: weights for output pos s are flat elements s*9 .. s*9+8
    const float* kwb = kw + (size_t)b * KK * HW + (size_t)s * 9;
    float wv[9];
    float norm = 1e-8f;
#pragma unroll
    for (int p = 0; p < 9; ++p) { wv[p] = kwb[p] * HAM[p]; norm += wv[p]; }
    float inv = 1.f / norm;
#pragma unroll
    for (int p = 0; p < 9; ++p) wv[p] *= inv;
    // reflect padding indices (np 'reflect': -1 -> 1, H -> H-2)
    int hm = (h == 0) ? 1 : h - 1;
    int hp = (h == Hd - 1) ? Hd - 2 : h + 1;
    int wm = (w == 0) ? 1 : w - 1;
    int wp = (w == Wd - 1) ? Wd - 2 : w + 1;
    int rows[3] = {hm * Wd, h * Wd, hp * Wd};
    int cols[3] = {wm, w, wp};
    const float* xb = x + (size_t)b * Cd * HW;
    float* ob = out + (size_t)b * Cd * HW;
    for (int c = 0; c < Cd; ++c) {
        const float* xc = xb + (size_t)c * HW;
        float agg = 0.f;
#pragma unroll
        for (int i = 0; i < 3; ++i)
#pragma unroll
            for (int j = 0; j < 3; ++j)
                agg = fmaf(xc[rows[i] + cols[j]], wv[i * 3 + j], agg);
        ob[(size_t)c * HW + s] = 2.f * xc[s] - agg;   // x + (x - agg)
    }
}

extern "C" void kernel_launch(void* const* d_in, const int* in_sizes, int n_in,
                              void* d_out, int out_size, void* d_ws, size_t ws_size,
                              hipStream_t stream) {
    const float* x      = (const float*)d_in[0];
    const float* w_comp = (const float*)d_in[1];
    const float* w_gen  = (const float*)d_in[2];
    const float* b_gen  = (const float*)d_in[3];
    float* out  = (float*)d_out;
    float* comp = (float*)d_ws;                        // 4*64*65536 floats = 64 MiB
    float* kw   = comp + (size_t)Bd * CM * HW;         // 4*9*65536 floats = 9 MiB

    int nThreads = Bd * HW;          // 262144 positions
    int nBlocks  = nThreads / 256;   // 1024

    compress_kernel<<<nBlocks, 256, 0, stream>>>(x, w_comp, comp);
    kwgen_kernel<<<nBlocks, 256, 0, stream>>>(comp, w_gen, b_gen, kw);
    agg_kernel<<<nBlocks, 256, 0, stream>>>(x, kw, out);
}

// Round 2
// 801.053 us; speedup vs baseline: 1.3407x; 1.3407x over previous
//
#include <hip/hip_runtime.h>

#define Bd 4
#define Cd 256
#define Hd 256
#define Wd 256
#define HW 65536
#define CM 64
#define KK 9
#define CG 32   // channels per wave in agg

// ---------------- Kernel A: 1x1 compression: comp[b,o,s] = sum_c x[b,c,s]*w_comp[o,c]
__global__ __launch_bounds__(256) void compress_kernel(
    const float* __restrict__ x, const float* __restrict__ w_comp,
    float* __restrict__ comp)
{
    int gid = blockIdx.x * 256 + threadIdx.x;   // 0..262143
    int b = gid >> 16;
    int s = gid & (HW - 1);
    const float* xb = x + (size_t)b * Cd * HW + s;
    float acc[CM];
#pragma unroll
    for (int o = 0; o < CM; ++o) acc[o] = 0.f;
    for (int c = 0; c < Cd; c += 4) {
        float x0 = xb[(size_t)(c + 0) * HW];
        float x1 = xb[(size_t)(c + 1) * HW];
        float x2 = xb[(size_t)(c + 2) * HW];
        float x3 = xb[(size_t)(c + 3) * HW];
#pragma unroll
        for (int o = 0; o < CM; ++o) {
            const float* wr = w_comp + o * Cd + c;   // uniform -> s_load
            acc[o] = fmaf(x0, wr[0], acc[o]);
            acc[o] = fmaf(x1, wr[1], acc[o]);
            acc[o] = fmaf(x2, wr[2], acc[o]);
            acc[o] = fmaf(x3, wr[3], acc[o]);
        }
    }
    float* ob = comp + (size_t)b * CM * HW + s;
#pragma unroll
    for (int o = 0; o < CM; ++o) ob[(size_t)o * HW] = acc[o];
}

// ---------------- Kernel B: 3x3 conv (zero pad) + bias + softmax over 9 taps
// One block = one (b,h) row; 4 waves cover 4 quarter-rows (lane-per-position).
// w_gen staged in LDS as wlds[c][t][12] (broadcast reads). Neighbors via shuffle.
__global__ __launch_bounds__(256) void kwgen_kernel(
    const float* __restrict__ comp, const float* __restrict__ w_gen,
    const float* __restrict__ b_gen, float* __restrict__ kw)
{
    __shared__ float wlds[CM][KK][12];
    // w_gen flat layout [t][c][3][3]: i = t*(CM*9) + c*9 + p
    for (int i = threadIdx.x; i < KK * CM * 9; i += 256) {
        int t = i / (CM * 9);
        int r = i - t * (CM * 9);
        int c = r / 9;
        int p = r - c * 9;
        wlds[c][t][p] = w_gen[i];
    }
    __syncthreads();

    int lane = threadIdx.x & 63;
    int q    = threadIdx.x >> 6;
    int b    = blockIdx.x >> 8;
    int h    = blockIdx.x & 255;
    int w    = q * 64 + lane;
    bool hmv = h > 0, hpv = h < Hd - 1;

    float acc[KK];
#pragma unroll
    for (int t = 0; t < KK; ++t) acc[t] = b_gen[t];

    const float* cb = comp + (size_t)b * CM * HW + h * Wd;
    for (int c = 0; c < CM; ++c) {
        const float* row = cb + (size_t)c * HW;
        float xm = hmv ? row[w - Wd] : 0.f;
        float xc = row[w];
        float xp = hpv ? row[w + Wd] : 0.f;
        float Lm = __shfl_up(xm, 1), Lc = __shfl_up(xc, 1), Lp = __shfl_up(xp, 1);
        float Rm = __shfl_down(xm, 1), Rc = __shfl_down(xc, 1), Rp = __shfl_down(xp, 1);
        if (lane == 0) {
            if (w == 0) { Lm = 0.f; Lc = 0.f; Lp = 0.f; }
            else {
                Lm = hmv ? row[w - 1 - Wd] : 0.f;
                Lc = row[w - 1];
                Lp = hpv ? row[w - 1 + Wd] : 0.f;
            }
        }
        if (lane == 63) {
            if (w == Wd - 1) { Rm = 0.f; Rc = 0.f; Rp = 0.f; }
            else {
                Rm = hmv ? row[w + 1 - Wd] : 0.f;
                Rc = row[w + 1];
                Rp = hpv ? row[w + 1 + Wd] : 0.f;
            }
        }
        float nb[9] = {Lm, xm, Rm, Lc, xc, Rc, Lp, xp, Rp};
#pragma unroll
        for (int t = 0; t < KK; ++t) {
            const float* wt = &wlds[c][t][0];
#pragma unroll
            for (int p = 0; p < 9; ++p)
                acc[t] = fmaf(nb[p], wt[p], acc[t]);
        }
    }
    // softmax over the 9 taps
    float m = acc[0];
#pragma unroll
    for (int t = 1; t < KK; ++t) m = fmaxf(m, acc[t]);
    float sum = 0.f;
#pragma unroll
    for (int t = 0; t < KK; ++t) { acc[t] = __expf(acc[t] - m); sum += acc[t]; }
    float inv = 1.f / sum;
    int s = h * Wd + w;
    float* ob = kw + (size_t)b * KK * HW + s;
#pragma unroll
    for (int t = 0; t < KK; ++t) ob[(size_t)t * HW] = acc[t] * inv;
}

// ---------------- Kernel C: view-scramble gather + hamming renorm + reflect aggregation
// Wave per (b, h, cgroup): lane covers 4 columns (float4); column neighbors via shuffle.
__global__ __launch_bounds__(256) void agg_kernel(
    const float* __restrict__ x, const float* __restrict__ kw,
    float* __restrict__ out)
{
    const float HAM[9] = {0.0064f, 0.08f, 0.0064f,
                          0.08f,   1.0f,  0.08f,
                          0.0064f, 0.08f, 0.0064f};
    int lane = threadIdx.x & 63;
    int wid  = threadIdx.x >> 6;
    int blk  = blockIdx.x;           // 2048 blocks: [b(4)][cg(8)][h4(64)]
    int h4 = blk & 63;
    int cg = (blk >> 6) & 7;
    int b  = blk >> 9;
    int h  = h4 * 4 + wid;
    int hm = (h == 0) ? 1 : h - 1;
    int hp = (h == Hd - 1) ? Hd - 2 : h + 1;

    // load + hamming-normalize the 4 positions' tap weights (view-scramble gather)
    float wv[4][9];
    {
        const float4* kv = (const float4*)(kw + (size_t)b * KK * HW
                                              + (size_t)h * (Wd * 9) + lane * 36);
        float t[36];
#pragma unroll
        for (int i = 0; i < 9; ++i) {
            float4 v = kv[i];
            t[i * 4 + 0] = v.x; t[i * 4 + 1] = v.y;
            t[i * 4 + 2] = v.z; t[i * 4 + 3] = v.w;
        }
#pragma unroll
        for (int j = 0; j < 4; ++j) {
            float s = 1e-8f;
#pragma unroll
            for (int p = 0; p < 9; ++p) { float u = t[j * 9 + p] * HAM[p]; wv[j][p] = u; s += u; }
            float inv = 1.f / s;
#pragma unroll
            for (int p = 0; p < 9; ++p) wv[j][p] *= inv;
        }
    }

    const float* xb = x + (size_t)b * Cd * HW;
    float* ob = out + (size_t)b * Cd * HW;
    int c0 = cg * CG;
    for (int c = c0; c < c0 + CG; ++c) {
        const float* xc0 = xb + (size_t)c * HW;
        float4 am = ((const float4*)(xc0 + hm * Wd))[lane];
        float4 ac = ((const float4*)(xc0 + h  * Wd))[lane];
        float4 ap = ((const float4*)(xc0 + hp * Wd))[lane];
        float Lm = __shfl_up(am.w, 1), Lc = __shfl_up(ac.w, 1), Lp = __shfl_up(ap.w, 1);
        float Rm = __shfl_down(am.x, 1), Rc = __shfl_down(ac.x, 1), Rp = __shfl_down(ap.x, 1);
        if (lane == 0)  { Lm = am.y; Lc = ac.y; Lp = ap.y; }   // reflect w=-1 -> w=1
        if (lane == 63) { Rm = am.z; Rc = ac.z; Rp = ap.z; }   // reflect w=256 -> w=254
        float em[6] = {Lm, am.x, am.y, am.z, am.w, Rm};
        float ec[6] = {Lc, ac.x, ac.y, ac.z, ac.w, Rc};
        float ep[6] = {Lp, ap.x, ap.y, ap.z, ap.w, Rp};
        float o4[4];
#pragma unroll
        for (int j = 0; j < 4; ++j) {
            float agg = em[j] * wv[j][0];
            agg = fmaf(em[j + 1], wv[j][1], agg);
            agg = fmaf(em[j + 2], wv[j][2], agg);
            agg = fmaf(ec[j],     wv[j][3], agg);
            agg = fmaf(ec[j + 1], wv[j][4], agg);
            agg = fmaf(ec[j + 2], wv[j][5], agg);
            agg = fmaf(ep[j],     wv[j][6], agg);
            agg = fmaf(ep[j + 1], wv[j][7], agg);
            agg = fmaf(ep[j + 2], wv[j][8], agg);
            o4[j] = 2.f * ec[j + 1] - agg;
        }
        float4 o = {o4[0], o4[1], o4[2], o4[3]};
        ((float4*)(ob + (size_t)c * HW + h * Wd))[lane] = o;
    }
}

extern "C" void kernel_launch(void* const* d_in, const int* in_sizes, int n_in,
                              void* d_out, int out_size, void* d_ws, size_t ws_size,
                              hipStream_t stream) {
    const float* x      = (const float*)d_in[0];
    const float* w_comp = (const float*)d_in[1];
    const float* w_gen  = (const float*)d_in[2];
    const float* b_gen  = (const float*)d_in[3];
    float* out  = (float*)d_out;
    float* comp = (float*)d_ws;                        // 4*64*65536 floats = 64 MiB
    float* kw   = comp + (size_t)Bd * CM * HW;         // 4*9*65536 floats = 9 MiB

    compress_kernel<<<1024, 256, 0, stream>>>(x, w_comp, comp);
    kwgen_kernel<<<1024, 256, 0, stream>>>(comp, w_gen, b_gen, kw);
    agg_kernel<<<2048, 256, 0, stream>>>(x, kw, out);
}